// Round 1
// baseline (3627.457 us; speedup 1.0000x reference)
//
#include <hip/hip_runtime.h>
#include <hip/hip_bf16.h>

// Problem constants
#define B_  32
#define T_  512
#define D_  512
#define HD_ 64
#define HN_ 16
#define O_  512
#define M_  (B_ * T_)      // 16384 rows
#define NQ_ (HN_ * HD_)    // 1024 qkv cols

__device__ __forceinline__ float toF(float x) { return x; }
__device__ __forceinline__ float toF(__hip_bfloat16 x) { return __bfloat162float(x); }
__device__ __forceinline__ void storeC(float* p, float v) { *p = v; }
__device__ __forceinline__ void storeC(__hip_bfloat16* p, float v) { *p = __float2bfloat16(v); }

// ---------------------------------------------------------------------------
// Tiled f32 GEMM: C[M,N] = act(A[M,K] @ W[K,N] + bias[N])
// HEADW: W has layout (HN, K, 64) (per-head), col n -> W[n>>6][k][n&63].
//        TILE_N==64 and n0%64==0 so each block's B-tile is within one head.
// ACT: 0 none, 1 relu, 2 tanh
// ---------------------------------------------------------------------------
template <int ACT, bool HEADW, typename TA, typename TO>
__global__ __launch_bounds__(256) void gemm_kernel(
    const TA* __restrict__ A, const float* __restrict__ W,
    const float* __restrict__ bias, TO* __restrict__ C,
    int M, int N, int K)
{
    __shared__ float As[64][17];
    __shared__ float Bs[16][65];
    const int tid = threadIdx.x;
    const int m0 = blockIdx.y * 64;
    const int n0 = blockIdx.x * 64;
    const int ty = tid >> 4, tx = tid & 15;

    float acc[4][4] = {};

    for (int k0 = 0; k0 < K; k0 += 16) {
        // A tile 64x16: thread loads 4 consecutive
        {
            const int r = tid >> 2, c0 = (tid & 3) * 4;
            const TA* ap = A + (size_t)(m0 + r) * K + k0 + c0;
#pragma unroll
            for (int i = 0; i < 4; i++) As[r][c0 + i] = toF(ap[i]);
        }
        // B tile 16x64
        {
            const int kr = tid >> 4, c0 = (tid & 15) * 4;
            const float* wp;
            if (HEADW)
                wp = W + ((size_t)(n0 >> 6) * K + (k0 + kr)) * 64 + c0;
            else
                wp = W + (size_t)(k0 + kr) * N + n0 + c0;
#pragma unroll
            for (int i = 0; i < 4; i++) Bs[kr][c0 + i] = wp[i];
        }
        __syncthreads();
#pragma unroll
        for (int kk = 0; kk < 16; kk++) {
            float a[4], b[4];
#pragma unroll
            for (int i = 0; i < 4; i++) a[i] = As[ty * 4 + i][kk];
#pragma unroll
            for (int j = 0; j < 4; j++) b[j] = Bs[kk][tx * 4 + j];
#pragma unroll
            for (int i = 0; i < 4; i++)
#pragma unroll
                for (int j = 0; j < 4; j++) acc[i][j] = fmaf(a[i], b[j], acc[i][j]);
        }
        __syncthreads();
    }

#pragma unroll
    for (int i = 0; i < 4; i++) {
        const int m = m0 + ty * 4 + i;
#pragma unroll
        for (int j = 0; j < 4; j++) {
            const int n = n0 + tx * 4 + j;
            float v = acc[i][j] + bias[n];
            if (ACT == 1) v = fmaxf(v, 0.f);
            else if (ACT == 2) v = tanhf(v);
            storeC(&C[(size_t)m * N + n], v);
        }
    }
}

// ---------------------------------------------------------------------------
// Causal attention, flash-style. One block = (b, h, 64-query-row block).
// q/k/v stored bf16 in concat layout: x[(b*T+t)*1024 + h*64 + f].
// Output overwrites this block's own q rows (read into LDS first).
// ---------------------------------------------------------------------------
__global__ __launch_bounds__(256) void attn_kernel(
    const __hip_bfloat16* __restrict__ Kb, const __hip_bfloat16* __restrict__ Vb,
    __hip_bfloat16* __restrict__ QC)
{
    const int bid = blockIdx.x;
    const int rb = bid & 7;          // T/64 = 8 row blocks
    const int h = (bid >> 3) & 15;
    const int b = bid >> 7;

    __shared__ float qs[64][65];
    __shared__ float kvs[64][65];    // shared between K and V phases
    __shared__ float ps[64][65];

    const int tid = threadIdx.x;
    const int r = tid >> 2;          // local query row 0..63
    const int g = tid & 3;           // col group: 16 cols each

    const size_t base_q = ((size_t)b * T_ + rb * 64) * NQ_ + h * 64;

    // load q rows into LDS
    {
        const int rr = tid >> 2, f0 = (tid & 3) * 16;
        const __hip_bfloat16* qp = QC + base_q + (size_t)rr * NQ_ + f0;
        for (int i = 0; i < 16; i++) qs[rr][f0 + i] = __bfloat162float(qp[i]);
    }

    float o[16];
#pragma unroll
    for (int i = 0; i < 16; i++) o[i] = 0.f;
    float mprev = -1e30f, l = 0.f;
    const int t_glob = rb * 64 + r;

    for (int sb = 0; sb <= rb; sb++) {
        __syncthreads();  // previous iteration done with kvs/ps (also covers q load)
        // load K block
        {
            const int rr = tid >> 2, f0 = (tid & 3) * 16;
            const __hip_bfloat16* kp = Kb + ((size_t)b * T_ + sb * 64 + rr) * NQ_ + h * 64 + f0;
            for (int i = 0; i < 16; i++) kvs[rr][f0 + i] = __bfloat162float(kp[i]);
        }
        __syncthreads();
        // scores for this thread's 16 s values
        float sc[16];
        float bmax = -1e30f;
#pragma unroll
        for (int j = 0; j < 16; j++) {
            const int sl = g * 16 + j;
            const int s_glob = sb * 64 + sl;
            float a = 0.f;
#pragma unroll
            for (int f = 0; f < 64; f++) a = fmaf(qs[r][f], kvs[sl][f], a);
            a *= 0.125f;  // 1/sqrt(64)
            if (s_glob > t_glob) a = -1e30f;
            sc[j] = a;
            bmax = fmaxf(bmax, a);
        }
        // reduce max across the 4 lanes sharing row r (consecutive lanes)
        bmax = fmaxf(bmax, __shfl_xor(bmax, 1));
        bmax = fmaxf(bmax, __shfl_xor(bmax, 2));
        const float mnew = fmaxf(mprev, bmax);
        const float scale = expf(mprev - mnew);
        float psum = 0.f;
#pragma unroll
        for (int j = 0; j < 16; j++) {
            const float p = (sc[j] <= -1e29f) ? 0.f : expf(sc[j] - mnew);
            ps[r][g * 16 + j] = p;
            psum += p;
        }
        psum += __shfl_xor(psum, 1);
        psum += __shfl_xor(psum, 2);
        l = l * scale + psum;
        mprev = mnew;
#pragma unroll
        for (int i = 0; i < 16; i++) o[i] *= scale;
        __syncthreads();  // ps written, everyone done reading kvs (K)
        // load V block into the same buffer
        {
            const int rr = tid >> 2, f0 = (tid & 3) * 16;
            const __hip_bfloat16* vp = Vb + ((size_t)b * T_ + sb * 64 + rr) * NQ_ + h * 64 + f0;
            for (int i = 0; i < 16; i++) kvs[rr][f0 + i] = __bfloat162float(vp[i]);
        }
        __syncthreads();
        // o += P @ V  (this thread: row r, cols g*16..g*16+15)
#pragma unroll
        for (int j = 0; j < 64; j++) {
            const float p = ps[r][j];
#pragma unroll
            for (int i = 0; i < 16; i++) o[i] = fmaf(p, kvs[j][g * 16 + i], o[i]);
        }
    }

    const float inv_l = 1.f / l;
    __hip_bfloat16* op = QC + base_q + (size_t)r * NQ_ + g * 16;
    for (int i = 0; i < 16; i++) op[i] = __float2bfloat16(o[i] * inv_l);
}

// ---------------------------------------------------------------------------
// Row LayerNorm in place: io[row,:] = LN(io[row,:] + add[row,:]) * w + b
// One block (256 threads) per 512-wide row.
// ---------------------------------------------------------------------------
__global__ __launch_bounds__(256) void ln_add_kernel(
    float* __restrict__ io, const float* __restrict__ add,
    const float* __restrict__ w, const float* __restrict__ bias)
{
    __shared__ float sbuf[4];
    const int row = blockIdx.x;
    const int tid = threadIdx.x;
    const size_t base = (size_t)row * O_;

    float x0 = io[base + tid] + add[base + tid];
    float x1 = io[base + 256 + tid] + add[base + 256 + tid];

    float s = x0 + x1;
#pragma unroll
    for (int off = 32; off >= 1; off >>= 1) s += __shfl_xor(s, off);
    if ((tid & 63) == 0) sbuf[tid >> 6] = s;
    __syncthreads();
    const float mean = (sbuf[0] + sbuf[1] + sbuf[2] + sbuf[3]) * (1.f / O_);
    __syncthreads();

    const float d0 = x0 - mean, d1 = x1 - mean;
    float ss = d0 * d0 + d1 * d1;
#pragma unroll
    for (int off = 32; off >= 1; off >>= 1) ss += __shfl_xor(ss, off);
    if ((tid & 63) == 0) sbuf[tid >> 6] = ss;
    __syncthreads();
    const float var = (sbuf[0] + sbuf[1] + sbuf[2] + sbuf[3]) * (1.f / O_);
    const float inv = rsqrtf(var + 1e-5f);

    io[base + tid] = d0 * inv * w[tid] + bias[tid];
    io[base + 256 + tid] = d1 * inv * w[tid + 256] + bias[tid + 256];
}

// ---------------------------------------------------------------------------
extern "C" void kernel_launch(void* const* d_in, const int* in_sizes, int n_in,
                              void* d_out, int out_size, void* d_ws, size_t ws_size,
                              hipStream_t stream)
{
    const float* inputs = (const float*)d_in[0];
    const float* Wq = (const float*)d_in[1];
    const float* bq = (const float*)d_in[2];
    const float* Wk = (const float*)d_in[3];
    const float* bk = (const float*)d_in[4];
    const float* Wv = (const float*)d_in[5];
    const float* bv = (const float*)d_in[6];
    const float* Wr = (const float*)d_in[7];
    const float* br = (const float*)d_in[8];
    const float* Wo = (const float*)d_in[9];
    const float* bo = (const float*)d_in[10];
    const float* ln1w = (const float*)d_in[11];
    const float* ln1b = (const float*)d_in[12];
    const float* Wfc = (const float*)d_in[13];
    const float* bfc = (const float*)d_in[14];
    const float* ln2w = (const float*)d_in[15];
    const float* ln2b = (const float*)d_in[16];
    float* out = (float*)d_out;

    // Workspace layout (134,217,728 bytes total):
    //   qc : bf16 [M, 1024]  (q, then overwritten in-place by attention output)
    //   kb : bf16 [M, 1024]
    //   vb : bf16 [M, 1024]
    //   res: f32  [M, 512]   (reused as fc after ln1)
    char* ws = (char*)d_ws;
    __hip_bfloat16* qc = (__hip_bfloat16*)ws;
    __hip_bfloat16* kb = (__hip_bfloat16*)(ws + (size_t)33554432);
    __hip_bfloat16* vb = (__hip_bfloat16*)(ws + (size_t)67108864);
    float* res = (float*)(ws + (size_t)100663296);
    float* fc = res;  // reuse after ln1 consumed res

    const dim3 blk(256);

    // residual = inputs @ Wr + br
    gemm_kernel<0, false, float, float><<<dim3(O_ / 64, M_ / 64), blk, 0, stream>>>(
        inputs, Wr, br, res, M_, O_, D_);
    // q = relu(inputs @ Wq + bq), k = relu(...), v = tanh(...)  [bf16, concat layout]
    gemm_kernel<1, true, float, __hip_bfloat16><<<dim3(NQ_ / 64, M_ / 64), blk, 0, stream>>>(
        inputs, Wq, bq, qc, M_, NQ_, D_);
    gemm_kernel<1, true, float, __hip_bfloat16><<<dim3(NQ_ / 64, M_ / 64), blk, 0, stream>>>(
        inputs, Wk, bk, kb, M_, NQ_, D_);
    gemm_kernel<2, true, float, __hip_bfloat16><<<dim3(NQ_ / 64, M_ / 64), blk, 0, stream>>>(
        inputs, Wv, bv, vb, M_, NQ_, D_);
    // attention (writes concat result over qc)
    attn_kernel<<<dim3(B_ * HN_ * (T_ / 64)), blk, 0, stream>>>(kb, vb, qc);
    // out = tanh(concat @ Wo + bo)
    gemm_kernel<2, false, __hip_bfloat16, float><<<dim3(O_ / 64, M_ / 64), blk, 0, stream>>>(
        qc, Wo, bo, out, M_, O_, NQ_);
    // out = LN1(out + residual)
    ln_add_kernel<<<dim3(M_), blk, 0, stream>>>(out, res, ln1w, ln1b);
    // fc = relu(out @ Wfc + bfc)
    gemm_kernel<1, false, float, float><<<dim3(O_ / 64, M_ / 64), blk, 0, stream>>>(
        out, Wfc, bfc, fc, M_, O_, O_);
    // out = LN2(fc + out)
    ln_add_kernel<<<dim3(M_), blk, 0, stream>>>(out, fc, ln2w, ln2b);
}

// Round 2
// 428.093 us; speedup vs baseline: 8.4735x; 8.4735x over previous
//
#include <hip/hip_runtime.h>
#include <hip/hip_bf16.h>

// Problem constants
#define B_  32
#define T_  512
#define D_  512
#define HD_ 64
#define HN_ 16
#define O_  512
#define M_  (B_ * T_)      // 16384 rows
#define NQ_ (HN_ * HD_)    // 1024 qkv cols

typedef __bf16 bf16;
typedef __attribute__((ext_vector_type(8))) __bf16 bf16x8;
typedef __attribute__((ext_vector_type(4))) __bf16 bf16x4;
typedef __attribute__((ext_vector_type(4))) float f32x4;

static __device__ __forceinline__ f32x4 mfma16(bf16x8 a, bf16x8 b, f32x4 c) {
    return __builtin_amdgcn_mfma_f32_16x16x32_bf16(a, b, c, 0, 0, 0);
}

template <int ACT>
static __device__ __forceinline__ float apply_act(float v) {
    if constexpr (ACT == 1) return fmaxf(v, 0.f);
    else if constexpr (ACT == 2) return tanhf(v);
    else return v;
}

// ---------------------------------------------------------------------------
// Weight prep: Wt[n][k] (bf16) from f32 W.
// HEADW: W is [HN][K][64], n = h*64+f. Else W is [K][N].
// ---------------------------------------------------------------------------
template <bool HEADW>
__global__ __launch_bounds__(256) void transpose_w_kernel(
    const float* __restrict__ in, bf16* __restrict__ out, int K, int N)
{
    const int idx = blockIdx.x * 256 + threadIdx.x;
    if (idx >= N * K) return;
    const int n = idx / K, k = idx - n * K;
    float v;
    if constexpr (HEADW) v = in[((size_t)(n >> 6) * K + k) * 64 + (n & 63)];
    else                 v = in[(size_t)k * N + n];
    out[idx] = (bf16)v;
}

// ---------------------------------------------------------------------------
// MFMA GEMM: C[M,N] = act(A[M,K] @ Wt^T + bias), Wt stored [N][K] bf16.
// 128x128 tile, BK=64, 4 waves (2x2), each wave 64x64 (4x4 16x16 frags).
// AF32: A is f32 (convert during staging), else bf16.
// VSTORE: write transposed per-head layout vt[(b*16+h)*64+f][512]+t (bf16).
// ---------------------------------------------------------------------------
template <int ACT, bool AF32, bool VSTORE, typename TO>
__global__ __launch_bounds__(256) void mfma_gemm_kernel(
    const void* __restrict__ Av, const bf16* __restrict__ Wt,
    const float* __restrict__ bias, TO* __restrict__ C,
    int M, int N, int K)
{
    __shared__ bf16 As[128][72];   // row m, col k (pad 8 -> 2-way max aliasing)
    __shared__ bf16 Bs[128][72];   // row n, col k
    const int tid = threadIdx.x;
    const int m0 = blockIdx.y * 128;
    const int n0 = blockIdx.x * 128;
    const int lane = tid & 63;
    const int w = tid >> 6;
    const int wr = w >> 1, wc = w & 1;
    const int lr = lane & 15, lg = lane >> 4;

    f32x4 zero4 = {0.f, 0.f, 0.f, 0.f};
    f32x4 acc[4][4];
#pragma unroll
    for (int i = 0; i < 4; i++)
#pragma unroll
        for (int j = 0; j < 4; j++) acc[i][j] = zero4;

    for (int k0 = 0; k0 < K; k0 += 64) {
        // stage A tile (128 x 64)
#pragma unroll
        for (int i = 0; i < 4; i++) {
            const int c = tid + 256 * i;
            const int row = c >> 3, cc = c & 7;
            if constexpr (AF32) {
                const float* src = (const float*)Av + (size_t)(m0 + row) * K + k0 + cc * 8;
                f32x4 x0 = *(const f32x4*)src;
                f32x4 x1 = *(const f32x4*)(src + 4);
                bf16x8 v;
                v[0] = (bf16)x0[0]; v[1] = (bf16)x0[1]; v[2] = (bf16)x0[2]; v[3] = (bf16)x0[3];
                v[4] = (bf16)x1[0]; v[5] = (bf16)x1[1]; v[6] = (bf16)x1[2]; v[7] = (bf16)x1[3];
                *(bf16x8*)&As[row][cc * 8] = v;
            } else {
                *(bf16x8*)&As[row][cc * 8] =
                    *(const bf16x8*)((const bf16*)Av + (size_t)(m0 + row) * K + k0 + cc * 8);
            }
        }
        // stage B tile (128 n-rows x 64 k)
#pragma unroll
        for (int i = 0; i < 4; i++) {
            const int c = tid + 256 * i;
            const int row = c >> 3, cc = c & 7;
            *(bf16x8*)&Bs[row][cc * 8] =
                *(const bf16x8*)(Wt + (size_t)(n0 + row) * K + k0 + cc * 8);
        }
        __syncthreads();
#pragma unroll
        for (int kc = 0; kc < 2; kc++) {
            bf16x8 a[4], b[4];
#pragma unroll
            for (int mi = 0; mi < 4; mi++)
                a[mi] = *(const bf16x8*)&As[wr * 64 + mi * 16 + lr][kc * 32 + lg * 8];
#pragma unroll
            for (int nj = 0; nj < 4; nj++)
                b[nj] = *(const bf16x8*)&Bs[wc * 64 + nj * 16 + lr][kc * 32 + lg * 8];
#pragma unroll
            for (int mi = 0; mi < 4; mi++)
#pragma unroll
                for (int nj = 0; nj < 4; nj++)
                    acc[mi][nj] = mfma16(a[mi], b[nj], acc[mi][nj]);
        }
        __syncthreads();
    }

    // epilogue: D frag row = (lane>>4)*4+reg, col = lane&15
#pragma unroll
    for (int mi = 0; mi < 4; mi++) {
#pragma unroll
        for (int nj = 0; nj < 4; nj++) {
            const int n = n0 + wc * 64 + nj * 16 + lr;
            const float bias_n = bias[n];
            if constexpr (VSTORE) {
                const int mrow = m0 + wr * 64 + mi * 16 + lg * 4;
                const int bb = mrow >> 9, t = mrow & 511;
                const int hh = n >> 6, f = n & 63;
                bf16x4 pk;
#pragma unroll
                for (int r = 0; r < 4; r++)
                    pk[r] = (bf16)apply_act<ACT>(acc[mi][nj][r] + bias_n);
                *(bf16x4*)((bf16*)C + (((size_t)(bb * 16 + hh) * 64 + f) << 9) + t) = pk;
            } else {
#pragma unroll
                for (int r = 0; r < 4; r++) {
                    const int m = m0 + wr * 64 + mi * 16 + lg * 4 + r;
                    C[(size_t)m * N + n] = (TO)apply_act<ACT>(acc[mi][nj][r] + bias_n);
                }
            }
        }
    }
}

// ---------------------------------------------------------------------------
// MFMA flash attention. Block = (b, h, 128 q rows); 4 waves x 32 q rows each.
// K natural layout kb[(b*T+t)*1024 + h*64 + f]; V pre-transposed
// vt[((b*16+h)*64 + f)*512 + t]. Output bf16 in-place over QC's own q rows.
// ---------------------------------------------------------------------------
__global__ __launch_bounds__(256) void mfma_attn_kernel(
    const bf16* __restrict__ Kb, const bf16* __restrict__ Vt, bf16* __restrict__ QC)
{
    __shared__ bf16 Ks[64][72];       // kv row, f col
    __shared__ bf16 Vts[64][72];      // d row, kv col
    __shared__ bf16 Ps[4][32][72];    // per-wave P: q row, kv col

    const int bid = blockIdx.x;
    const int qb = bid & 3;
    const int h = (bid >> 2) & 15;
    const int b = bid >> 6;
    const int tid = threadIdx.x;
    const int lane = tid & 63;
    const int w = tid >> 6;
    const int lr = lane & 15, lg = lane >> 4;

    const int qrow0 = qb * 128 + w * 32;
    const size_t qbase = ((size_t)b * T_ + qrow0) * NQ_ + h * 64;

    // Q fragments in registers (read before any QC write)
    bf16x8 qf[2][2];
#pragma unroll
    for (int mi = 0; mi < 2; mi++)
#pragma unroll
        for (int kc = 0; kc < 2; kc++)
            qf[mi][kc] = *(const bf16x8*)(QC + qbase + (size_t)(mi * 16 + lr) * NQ_ + kc * 32 + lg * 8);

    f32x4 zero4 = {0.f, 0.f, 0.f, 0.f};
    f32x4 o[2][4];
    float m_st[2][4], l_st[2][4];
#pragma unroll
    for (int mi = 0; mi < 2; mi++) {
#pragma unroll
        for (int dj = 0; dj < 4; dj++) o[mi][dj] = zero4;
#pragma unroll
        for (int r = 0; r < 4; r++) { m_st[mi][r] = -1e30f; l_st[mi][r] = 0.f; }
    }

    const int nsb = 2 * qb + 2;
    const int bh = b * HN_ + h;

    for (int sb = 0; sb < nsb; sb++) {
        if (sb > 0) __syncthreads();   // all waves done reading previous K/V
        // cooperative load K tile (64 kv x 64 f) and Vt tile (64 d x 64 kv)
#pragma unroll
        for (int i = 0; i < 2; i++) {
            const int c = tid + 256 * i;
            const int row = c >> 3, cc = c & 7;
            *(bf16x8*)&Ks[row][cc * 8] =
                *(const bf16x8*)(Kb + ((size_t)b * T_ + sb * 64 + row) * NQ_ + h * 64 + cc * 8);
            *(bf16x8*)&Vts[row][cc * 8] =
                *(const bf16x8*)(Vt + ((size_t)bh * 64 + row) * T_ + sb * 64 + cc * 8);
        }
        __syncthreads();

        if (sb * 64 <= qrow0 + 31) {   // wave has unmasked work in this kv block
            // S = Q K^T  (2 mi x 4 nj tiles x 2 k-chunks)
            f32x4 sc[2][4];
#pragma unroll
            for (int mi = 0; mi < 2; mi++)
#pragma unroll
                for (int nj = 0; nj < 4; nj++) sc[mi][nj] = zero4;
#pragma unroll
            for (int kc = 0; kc < 2; kc++) {
                bf16x8 kf[4];
#pragma unroll
                for (int nj = 0; nj < 4; nj++)
                    kf[nj] = *(const bf16x8*)&Ks[nj * 16 + lr][kc * 32 + lg * 8];
#pragma unroll
                for (int mi = 0; mi < 2; mi++)
#pragma unroll
                    for (int nj = 0; nj < 4; nj++)
                        sc[mi][nj] = mfma16(qf[mi][kc], kf[nj], sc[mi][nj]);
            }
            // online softmax (row = q, held by 16 lanes sharing lg; reduce over lr)
            float scl[2][4];
#pragma unroll
            for (int mi = 0; mi < 2; mi++) {
#pragma unroll
                for (int r = 0; r < 4; r++) {
                    const int qg = qrow0 + mi * 16 + lg * 4 + r;
                    float tm = -1e30f;
#pragma unroll
                    for (int nj = 0; nj < 4; nj++) {
                        float s = sc[mi][nj][r] * 0.125f;
                        const int kg = sb * 64 + nj * 16 + lr;
                        s = (kg > qg) ? -1e30f : s;
                        sc[mi][nj][r] = s;
                        tm = fmaxf(tm, s);
                    }
                    tm = fmaxf(tm, __shfl_xor(tm, 1));
                    tm = fmaxf(tm, __shfl_xor(tm, 2));
                    tm = fmaxf(tm, __shfl_xor(tm, 4));
                    tm = fmaxf(tm, __shfl_xor(tm, 8));
                    const float mn = fmaxf(m_st[mi][r], tm);
                    const float sf = __expf(m_st[mi][r] - mn);
                    m_st[mi][r] = mn;
                    float ts = 0.f;
#pragma unroll
                    for (int nj = 0; nj < 4; nj++) {
                        const float pv = __expf(sc[mi][nj][r] - mn);
                        Ps[w][mi * 16 + lg * 4 + r][nj * 16 + lr] = (bf16)pv;
                        ts += pv;
                    }
                    ts += __shfl_xor(ts, 1);
                    ts += __shfl_xor(ts, 2);
                    ts += __shfl_xor(ts, 4);
                    ts += __shfl_xor(ts, 8);
                    l_st[mi][r] = l_st[mi][r] * sf + ts;
                    scl[mi][r] = sf;
                }
            }
            // rescale O
#pragma unroll
            for (int mi = 0; mi < 2; mi++)
#pragma unroll
                for (int dj = 0; dj < 4; dj++)
#pragma unroll
                    for (int r = 0; r < 4; r++) o[mi][dj][r] *= scl[mi][r];
            // O += P @ V   (P from wave-private LDS; Vt gives contiguous B-frags)
#pragma unroll
            for (int kc = 0; kc < 2; kc++) {
                bf16x8 pa[2], vf[4];
#pragma unroll
                for (int mi = 0; mi < 2; mi++)
                    pa[mi] = *(const bf16x8*)&Ps[w][mi * 16 + lr][kc * 32 + lg * 8];
#pragma unroll
                for (int dj = 0; dj < 4; dj++)
                    vf[dj] = *(const bf16x8*)&Vts[dj * 16 + lr][kc * 32 + lg * 8];
#pragma unroll
                for (int mi = 0; mi < 2; mi++)
#pragma unroll
                    for (int dj = 0; dj < 4; dj++)
                        o[mi][dj] = mfma16(pa[mi], vf[dj], o[mi][dj]);
            }
        }
    }

    // normalize + store (in place over this wave's q rows)
#pragma unroll
    for (int mi = 0; mi < 2; mi++) {
#pragma unroll
        for (int r = 0; r < 4; r++) {
            const float inv = 1.f / l_st[mi][r];
            const size_t rowoff = qbase + (size_t)(mi * 16 + lg * 4 + r) * NQ_;
#pragma unroll
            for (int dj = 0; dj < 4; dj++)
                QC[rowoff + dj * 16 + lr] = (bf16)(o[mi][dj][r] * inv);
        }
    }
}

// ---------------------------------------------------------------------------
// Row LayerNorm in place: io[row,:] = LN(io[row,:] + add[row,:]) * w + b
// ---------------------------------------------------------------------------
__global__ __launch_bounds__(256) void ln_add_kernel(
    float* __restrict__ io, const bf16* __restrict__ add,
    const float* __restrict__ w, const float* __restrict__ bias)
{
    __shared__ float sbuf[4];
    const int row = blockIdx.x;
    const int tid = threadIdx.x;
    const size_t base = (size_t)row * O_;

    float x0 = io[base + tid] + (float)add[base + tid];
    float x1 = io[base + 256 + tid] + (float)add[base + 256 + tid];

    float s = x0 + x1;
#pragma unroll
    for (int off = 32; off >= 1; off >>= 1) s += __shfl_xor(s, off);
    if ((tid & 63) == 0) sbuf[tid >> 6] = s;
    __syncthreads();
    const float mean = (sbuf[0] + sbuf[1] + sbuf[2] + sbuf[3]) * (1.f / O_);
    __syncthreads();

    const float d0 = x0 - mean, d1 = x1 - mean;
    float ss = d0 * d0 + d1 * d1;
#pragma unroll
    for (int off = 32; off >= 1; off >>= 1) ss += __shfl_xor(ss, off);
    if ((tid & 63) == 0) sbuf[tid >> 6] = ss;
    __syncthreads();
    const float var = (sbuf[0] + sbuf[1] + sbuf[2] + sbuf[3]) * (1.f / O_);
    const float inv = rsqrtf(var + 1e-5f);

    io[base + tid] = d0 * inv * w[tid] + bias[tid];
    io[base + 256 + tid] = d1 * inv * w[tid + 256] + bias[tid + 256];
}

// ---------------------------------------------------------------------------
extern "C" void kernel_launch(void* const* d_in, const int* in_sizes, int n_in,
                              void* d_out, int out_size, void* d_ws, size_t ws_size,
                              hipStream_t stream)
{
    const float* inputs = (const float*)d_in[0];
    const float* Wq = (const float*)d_in[1];
    const float* bq = (const float*)d_in[2];
    const float* Wk = (const float*)d_in[3];
    const float* bk = (const float*)d_in[4];
    const float* Wv = (const float*)d_in[5];
    const float* bv = (const float*)d_in[6];
    const float* Wr = (const float*)d_in[7];
    const float* br = (const float*)d_in[8];
    const float* Wo = (const float*)d_in[9];
    const float* bo = (const float*)d_in[10];
    const float* ln1w = (const float*)d_in[11];
    const float* ln1b = (const float*)d_in[12];
    const float* Wfc = (const float*)d_in[13];
    const float* bfc = (const float*)d_in[14];
    const float* ln2w = (const float*)d_in[15];
    const float* ln2b = (const float*)d_in[16];
    float* out = (float*)d_out;

    // Workspace layout (117 MB):
    const size_t MB = 1024 * 1024;
    char* ws = (char*)d_ws;
    bf16* qc   = (bf16*)(ws);               // 32MB [M][1024] q -> attn out (in place)
    bf16* kb   = (bf16*)(ws + 32 * MB);     // 32MB [M][1024]
    bf16* vt   = (bf16*)(ws + 64 * MB);     // 32MB [(b*16+h)*64+f][512]
    bf16* res  = (bf16*)(ws + 96 * MB);     // 16MB [M][512] residual, then fc
    bf16* wqt  = (bf16*)(ws + 112 * MB);    // 1MB  [1024][512]
    bf16* wkt  = (bf16*)(ws + 113 * MB);    // 1MB
    bf16* wvt  = (bf16*)(ws + 114 * MB);    // 1MB
    bf16* wrt  = (bf16*)(ws + 115 * MB);    // 0.5MB [512][512]
    bf16* wot  = (bf16*)(ws + 115 * MB + 512 * 1024);  // 1MB [512][1024]
    bf16* wfct = (bf16*)(ws + 116 * MB + 512 * 1024);  // 0.5MB [512][512]
    bf16* fcb = res;  // reuse after ln1 consumed res

    const dim3 blk(256);

    // weight prep (bf16, [N][K])
    transpose_w_kernel<true ><<<dim3((NQ_ * D_) / 256), blk, 0, stream>>>(Wq, wqt, D_, NQ_);
    transpose_w_kernel<true ><<<dim3((NQ_ * D_) / 256), blk, 0, stream>>>(Wk, wkt, D_, NQ_);
    transpose_w_kernel<true ><<<dim3((NQ_ * D_) / 256), blk, 0, stream>>>(Wv, wvt, D_, NQ_);
    transpose_w_kernel<false><<<dim3((D_ * O_) / 256), blk, 0, stream>>>(Wr, wrt, D_, O_);
    transpose_w_kernel<false><<<dim3((NQ_ * O_) / 256), blk, 0, stream>>>(Wo, wot, NQ_, O_);
    transpose_w_kernel<false><<<dim3((O_ * O_) / 256), blk, 0, stream>>>(Wfc, wfct, O_, O_);

    // residual = inputs @ Wr + br  (bf16)
    mfma_gemm_kernel<0, true, false, bf16><<<dim3(O_ / 128, M_ / 128), blk, 0, stream>>>(
        inputs, wrt, br, res, M_, O_, D_);
    // q/k (relu, bf16), v (tanh, transposed store)
    mfma_gemm_kernel<1, true, false, bf16><<<dim3(NQ_ / 128, M_ / 128), blk, 0, stream>>>(
        inputs, wqt, bq, qc, M_, NQ_, D_);
    mfma_gemm_kernel<1, true, false, bf16><<<dim3(NQ_ / 128, M_ / 128), blk, 0, stream>>>(
        inputs, wkt, bk, kb, M_, NQ_, D_);
    mfma_gemm_kernel<2, true, true, bf16><<<dim3(NQ_ / 128, M_ / 128), blk, 0, stream>>>(
        inputs, wvt, bv, vt, M_, NQ_, D_);
    // attention (in place over qc)
    mfma_attn_kernel<<<dim3(B_ * HN_ * 4), blk, 0, stream>>>(kb, vt, qc);
    // out = tanh(concat @ Wo + bo)  (f32)
    mfma_gemm_kernel<2, false, false, float><<<dim3(O_ / 128, M_ / 128), blk, 0, stream>>>(
        qc, wot, bo, out, M_, O_, NQ_);
    // out = LN1(out + res)
    ln_add_kernel<<<dim3(M_), blk, 0, stream>>>(out, res, ln1w, ln1b);
    // fc = relu(out @ Wfc + bfc)  (bf16, reuses res)
    mfma_gemm_kernel<1, true, false, bf16><<<dim3(O_ / 128, M_ / 128), blk, 0, stream>>>(
        out, wfct, bfc, fcb, M_, O_, O_);
    // out = LN2(fc + out)
    ln_add_kernel<<<dim3(M_), blk, 0, stream>>>(out, fcb, ln2w, ln2b);
}

// Round 3
// 326.111 us; speedup vs baseline: 11.1234x; 1.3127x over previous
//
#include <hip/hip_runtime.h>
#include <hip/hip_bf16.h>

// Problem constants
#define B_  32
#define T_  512
#define D_  512
#define HD_ 64
#define HN_ 16
#define O_  512
#define M_  (B_ * T_)      // 16384 rows
#define NQ_ (HN_ * HD_)    // 1024 qkv cols

typedef __bf16 bf16;
typedef __attribute__((ext_vector_type(8))) __bf16 bf16x8;
typedef __attribute__((ext_vector_type(4))) __bf16 bf16x4;
typedef __attribute__((ext_vector_type(4))) float f32x4;

static __device__ __forceinline__ f32x4 mfma16(bf16x8 a, bf16x8 b, f32x4 c) {
    return __builtin_amdgcn_mfma_f32_16x16x32_bf16(a, b, c, 0, 0, 0);
}

// Direct global->LDS 16B copy (CK-style addrspace casts via integer detour).
static __device__ __forceinline__ void load_lds_16B(const bf16* g, bf16* l) {
    __builtin_amdgcn_global_load_lds(
        (const __attribute__((address_space(1))) unsigned int*)(unsigned long long)g,
        (__attribute__((address_space(3))) unsigned int*)(unsigned long long)l,
        16, 0, 0);
}

// ---------------------------------------------------------------------------
// Weight prep: Wt[n][k] (bf16) from f32 W. HEADW: W is [HN][K][64], n=h*64+f.
// ---------------------------------------------------------------------------
template <bool HEADW>
__global__ __launch_bounds__(256) void transpose_w_kernel(
    const float* __restrict__ in, bf16* __restrict__ out, int K, int N)
{
    const int idx = blockIdx.x * 256 + threadIdx.x;
    if (idx >= N * K) return;
    const int n = idx / K, k = idx - n * K;
    float v;
    if constexpr (HEADW) v = in[((size_t)(n >> 6) * K + k) * 64 + (n & 63)];
    else                 v = in[(size_t)k * N + n];
    out[idx] = (bf16)v;
}

__global__ __launch_bounds__(256) void conv_input_kernel(
    const float* __restrict__ in, bf16* __restrict__ out)
{
    const size_t i = ((size_t)blockIdx.x * 256 + threadIdx.x) * 8;
    f32x4 x0 = *(const f32x4*)(in + i);
    f32x4 x1 = *(const f32x4*)(in + i + 4);
    bf16x8 v;
    v[0] = (bf16)x0[0]; v[1] = (bf16)x0[1]; v[2] = (bf16)x0[2]; v[3] = (bf16)x0[3];
    v[4] = (bf16)x1[0]; v[5] = (bf16)x1[1]; v[6] = (bf16)x1[2]; v[7] = (bf16)x1[3];
    *(bf16x8*)(out + i) = v;
}

__global__ __launch_bounds__(256) void pack_bias_kernel(
    const float* __restrict__ bq, const float* __restrict__ bk,
    const float* __restrict__ bv, float* __restrict__ ball)
{
    const int i = blockIdx.x * 256 + threadIdx.x;  // 0..3071
    float v = (i < 1024) ? bq[i] : (i < 2048) ? bk[i - 1024] : bv[i - 2048];
    ball[i] = v;
}

// ---------------------------------------------------------------------------
// Shared GEMM mainloop: 128x128 tile, BK=64, 4 waves (2x2), A[M][K] bf16,
// Wt[N][K] bf16. global_load_lds(16B) staging, XOR-swizzled (granule ^= row&7)
// via pre-swizzled per-lane GLOBAL addresses + XOR on the LDS read side.
// ---------------------------------------------------------------------------
__device__ __forceinline__ void gemm_mainloop(
    const bf16* __restrict__ A, const bf16* __restrict__ Wt,
    const int K, const int m0, const int n0, const int tid,
    bf16* As, bf16* Bs, f32x4 (&acc)[4][4])
{
    const int lane = tid & 63;
    const int w = tid >> 6;
    const int wr = w >> 1, wc = w & 1;
    const int lr = lane & 15, lg = lane >> 4;

    for (int k0 = 0; k0 < K; k0 += 64) {
#pragma unroll
        for (int i = 0; i < 4; i++) {
            const int p = i * 256 + tid;           // 16B chunk index in tile
            const int row = p >> 3;
            const int g = (p & 7) ^ (row & 7);     // inverse-swizzled source granule
            load_lds_16B(A + (size_t)(m0 + row) * K + k0 + g * 8, As + p * 8);
            load_lds_16B(Wt + (size_t)(n0 + row) * K + k0 + g * 8, Bs + p * 8);
        }
        __syncthreads();   // compiler drains vmcnt before s_barrier
#pragma unroll
        for (int kc = 0; kc < 2; kc++) {
            bf16x8 a[4], b[4];
#pragma unroll
            for (int mi = 0; mi < 4; mi++) {
                const int row = wr * 64 + mi * 16 + lr;
                a[mi] = *(const bf16x8*)&As[row * 64 + ((((kc << 2) | lg) ^ (row & 7)) << 3)];
            }
#pragma unroll
            for (int nj = 0; nj < 4; nj++) {
                const int row = wc * 64 + nj * 16 + lr;
                b[nj] = *(const bf16x8*)&Bs[row * 64 + ((((kc << 2) | lg) ^ (row & 7)) << 3)];
            }
#pragma unroll
            for (int mi = 0; mi < 4; mi++)
#pragma unroll
                for (int nj = 0; nj < 4; nj++)
                    acc[mi][nj] = mfma16(a[mi], b[nj], acc[mi][nj]);
        }
        __syncthreads();
    }
}

// Fused QKV GEMM: N=3072 (q:0..1023 relu, k:1024..2047 relu, v:2048..3071 tanh
// with transposed per-head store). K=512.
__global__ __launch_bounds__(256) void gemm_qkv_kernel(
    const bf16* __restrict__ A, const bf16* __restrict__ Wall, const float* __restrict__ ball,
    bf16* __restrict__ qc, bf16* __restrict__ kb, bf16* __restrict__ vt)
{
    __shared__ bf16 As[128 * 64];
    __shared__ bf16 Bs[128 * 64];
    const int tid = threadIdx.x;
    const int m0 = blockIdx.y * 128;
    const int n0 = blockIdx.x * 128;
    f32x4 acc[4][4];
    const f32x4 zero4 = {0.f, 0.f, 0.f, 0.f};
#pragma unroll
    for (int i = 0; i < 4; i++)
#pragma unroll
        for (int j = 0; j < 4; j++) acc[i][j] = zero4;

    gemm_mainloop(A, Wall, 512, m0, n0, tid, As, Bs, acc);

    const int lane = tid & 63, w = tid >> 6;
    const int wr = w >> 1, wc = w & 1, lr = lane & 15, lg = lane >> 4;
    const int region = n0 >> 10;  // 0=q, 1=k, 2=v (n-tiles never straddle)
#pragma unroll
    for (int mi = 0; mi < 4; mi++) {
#pragma unroll
        for (int nj = 0; nj < 4; nj++) {
            const int n = n0 + wc * 64 + nj * 16 + lr;
            const float bn = ball[n];
            if (region == 2) {
                const int m = m0 + wr * 64 + mi * 16 + lg * 4;
                const int bb = m >> 9, t = m & 511;
                const int nn = n - 2048;
                const int hh = nn >> 6, f = nn & 63;
                bf16x4 st;
#pragma unroll
                for (int r = 0; r < 4; r++) st[r] = (bf16)tanhf(acc[mi][nj][r] + bn);
                *(bf16x4*)(vt + (((size_t)(bb * 16 + hh) * 64 + f) << 9) + t) = st;
            } else {
                bf16* dst = region ? kb : qc;
                const int nn = n & 1023;
#pragma unroll
                for (int r = 0; r < 4; r++) {
                    const int m = m0 + wr * 64 + mi * 16 + lg * 4 + r;
                    dst[(size_t)m * 1024 + nn] = (bf16)fmaxf(acc[mi][nj][r] + bn, 0.f);
                }
            }
        }
    }
}

// Standard GEMM: N=512 pitch. ACT: 0 none, 1 relu, 2 tanh. F32OUT: f32 vs bf16.
template <int ACT, bool F32OUT>
__global__ __launch_bounds__(256) void gemm_std_kernel(
    const bf16* __restrict__ A, const bf16* __restrict__ Wt,
    const float* __restrict__ bias, void* __restrict__ Cv, const int K)
{
    __shared__ bf16 As[128 * 64];
    __shared__ bf16 Bs[128 * 64];
    const int tid = threadIdx.x;
    const int m0 = blockIdx.y * 128;
    const int n0 = blockIdx.x * 128;
    f32x4 acc[4][4];
    const f32x4 zero4 = {0.f, 0.f, 0.f, 0.f};
#pragma unroll
    for (int i = 0; i < 4; i++)
#pragma unroll
        for (int j = 0; j < 4; j++) acc[i][j] = zero4;

    gemm_mainloop(A, Wt, K, m0, n0, tid, As, Bs, acc);

    const int lane = tid & 63, w = tid >> 6;
    const int wr = w >> 1, wc = w & 1, lr = lane & 15, lg = lane >> 4;
#pragma unroll
    for (int mi = 0; mi < 4; mi++) {
#pragma unroll
        for (int nj = 0; nj < 4; nj++) {
            const int n = n0 + wc * 64 + nj * 16 + lr;
            const float bn = bias[n];
#pragma unroll
            for (int r = 0; r < 4; r++) {
                const int m = m0 + wr * 64 + mi * 16 + lg * 4 + r;
                float v = acc[mi][nj][r] + bn;
                if constexpr (ACT == 1) v = fmaxf(v, 0.f);
                else if constexpr (ACT == 2) v = tanhf(v);
                if constexpr (F32OUT) ((float*)Cv)[(size_t)m * 512 + n] = v;
                else ((bf16*)Cv)[(size_t)m * 512 + n] = (bf16)v;
            }
        }
    }
}

// ---------------------------------------------------------------------------
// MFMA flash attention, swapped-operand form.
// Block = (b, h, 128 q rows); 4 waves x 32 q rows. S^T = mfma(K,Q) so each
// lane owns q = lane&15: softmax is in-register (15 fmax + 2 shfl per 16 rows).
// K rows stored in LDS under sigma() so S^T regs == PV B-frag layout directly.
// PV: O^T = mfma(V^T, P^T). Output in-place over QC's own q rows.
// ---------------------------------------------------------------------------
static __device__ __forceinline__ int sigma_k(int t) {
    // t (local kv) -> LDS row, inverse of tau(m)=32a+8c+4b+d for m=32a+16b+4c+d
    return (t & 32) | ((t & 4) << 2) | ((t & 24) >> 1) | (t & 3);
}

__global__ __launch_bounds__(256) void mfma_attn_kernel(
    const bf16* __restrict__ Kb, const bf16* __restrict__ Vt, bf16* __restrict__ QC)
{
    __shared__ bf16 Ks[64][72];   // sigma-permuted kv rows, f cols
    __shared__ bf16 Vts[64][72];  // d rows, kv cols

    const int bid = blockIdx.x;
    const int qb = bid & 3;
    const int h = (bid >> 2) & 15;
    const int b = bid >> 6;
    const int tid = threadIdx.x;
    const int lane = tid & 63;
    const int w = tid >> 6;
    const int lr = lane & 15, lg = lane >> 4;

    const int qrow0 = qb * 128 + w * 32;
    const size_t qbase = ((size_t)b * T_ + qrow0) * NQ_ + h * 64;

    // Q fragments (B-frag: col q=lr, k=f) -- read before any QC write
    bf16x8 qf[2][2];
#pragma unroll
    for (int mi = 0; mi < 2; mi++)
#pragma unroll
        for (int kc = 0; kc < 2; kc++)
            qf[mi][kc] = *(const bf16x8*)(QC + qbase + (size_t)(mi * 16 + lr) * NQ_ + kc * 32 + lg * 8);

    const f32x4 zero4 = {0.f, 0.f, 0.f, 0.f};
    f32x4 o[2][4];
    float m_st[2] = {-1e30f, -1e30f}, l_st[2] = {0.f, 0.f};
#pragma unroll
    for (int mi = 0; mi < 2; mi++)
#pragma unroll
        for (int dj = 0; dj < 4; dj++) o[mi][dj] = zero4;

    const int nsb = 2 * qb + 2;
    const int bh = b * HN_ + h;

    for (int sb = 0; sb < nsb; sb++) {
        if (sb > 0) __syncthreads();
        // cooperative stage: K (permuted rows) + Vt
#pragma unroll
        for (int i = 0; i < 2; i++) {
            const int c = tid + 256 * i;
            const int row = c >> 3, cc = c & 7;
            *(bf16x8*)&Ks[sigma_k(row)][cc * 8] =
                *(const bf16x8*)(Kb + ((size_t)b * T_ + sb * 64 + row) * NQ_ + h * 64 + cc * 8);
            *(bf16x8*)&Vts[row][cc * 8] =
                *(const bf16x8*)(Vt + ((size_t)bh * 64 + row) * T_ + sb * 64 + cc * 8);
        }
        __syncthreads();

        if (sb * 64 > qrow0 + 31) continue;   // wave fully masked (uniform per wave)

        // S^T = K Q^T : A=K rows (LDS order), B=Q cols
        f32x4 sc[2][4];
#pragma unroll
        for (int mi = 0; mi < 2; mi++)
#pragma unroll
            for (int nj = 0; nj < 4; nj++) sc[mi][nj] = zero4;
#pragma unroll
        for (int kc = 0; kc < 2; kc++) {
            bf16x8 kf[4];
#pragma unroll
            for (int nj = 0; nj < 4; nj++)
                kf[nj] = *(const bf16x8*)&Ks[nj * 16 + lr][kc * 32 + lg * 8];
#pragma unroll
            for (int mi = 0; mi < 2; mi++)
#pragma unroll
                for (int nj = 0; nj < 4; nj++)
                    sc[mi][nj] = mfma16(kf[nj], qf[mi][kc], sc[mi][nj]);
        }

        // scale + causal mask + in-register row max (actual kv via tau())
        const bool needmask = (sb * 64 + 63 > qrow0);
        float tm[2];
#pragma unroll
        for (int mi = 0; mi < 2; mi++) {
            const int qg = qrow0 + mi * 16 + lr;
            float mx = -1e30f;
#pragma unroll
            for (int nj = 0; nj < 4; nj++) {
                const int kvb = sb * 64 + ((nj >> 1) << 5) + ((nj & 1) << 2) + lg * 8;
#pragma unroll
                for (int r = 0; r < 4; r++) {
                    float s = sc[mi][nj][r] * 0.125f;
                    if (needmask && (kvb + r > qg)) s = -1e30f;
                    sc[mi][nj][r] = s;
                    mx = fmaxf(mx, s);
                }
            }
            mx = fmaxf(mx, __shfl_xor(mx, 16));
            mx = fmaxf(mx, __shfl_xor(mx, 32));
            tm[mi] = mx;
        }
        // defer-max (T13): skip O/l rescale when max didn't grow past m+8
        const bool defer = (tm[0] <= m_st[0] + 8.f) && (tm[1] <= m_st[1] + 8.f);
        if (!__all(defer)) {
#pragma unroll
            for (int mi = 0; mi < 2; mi++) {
                const float mn = fmaxf(m_st[mi], tm[mi]);
                const float sf = __expf(m_st[mi] - mn);
                m_st[mi] = mn;
                l_st[mi] *= sf;
#pragma unroll
                for (int dj = 0; dj < 4; dj++)
#pragma unroll
                    for (int r = 0; r < 4; r++) o[mi][dj][r] *= sf;
            }
        }
        // P = exp(S - m), row-sum, pack to bf16 (already in PV B-frag order)
        bf16x4 pk[2][4];
#pragma unroll
        for (int mi = 0; mi < 2; mi++) {
            float ts = 0.f;
#pragma unroll
            for (int nj = 0; nj < 4; nj++)
#pragma unroll
                for (int r = 0; r < 4; r++) {
                    const float p = __expf(sc[mi][nj][r] - m_st[mi]);
                    ts += p;
                    pk[mi][nj][r] = (bf16)p;
                }
            ts += __shfl_xor(ts, 16);
            ts += __shfl_xor(ts, 32);
            l_st[mi] += ts;
        }
        // O^T += V^T P^T : A=V^T rows d, B=P^T cols q (k=kv natural order)
#pragma unroll
        for (int kc = 0; kc < 2; kc++) {
            bf16x8 vf[4], pf[2];
#pragma unroll
            for (int mi = 0; mi < 2; mi++) {
                bf16x8 t;
#pragma unroll
                for (int r = 0; r < 4; r++) { t[r] = pk[mi][2 * kc][r]; t[r + 4] = pk[mi][2 * kc + 1][r]; }
                pf[mi] = t;
            }
#pragma unroll
            for (int dj = 0; dj < 4; dj++)
                vf[dj] = *(const bf16x8*)&Vts[dj * 16 + lr][kc * 32 + lg * 8];
#pragma unroll
            for (int mi = 0; mi < 2; mi++)
#pragma unroll
                for (int dj = 0; dj < 4; dj++)
                    o[mi][dj] = mfma16(vf[dj], pf[mi], o[mi][dj]);
        }
    }

    // normalize + in-place store (O^T: lane owns q=lr col, d=lg*4+r rows)
#pragma unroll
    for (int mi = 0; mi < 2; mi++) {
        const float inv = 1.f / l_st[mi];
        const size_t rowoff = qbase + (size_t)(mi * 16 + lr) * NQ_;
#pragma unroll
        for (int dj = 0; dj < 4; dj++) {
            bf16x4 st;
#pragma unroll
            for (int r = 0; r < 4; r++) st[r] = (bf16)(o[mi][dj][r] * inv);
            *(bf16x4*)(QC + rowoff + dj * 16 + lg * 4) = st;
        }
    }
}

// ---------------------------------------------------------------------------
// Row LayerNorm in place: io = LN(io + add) * w + b; optional bf16 copy out.
// ---------------------------------------------------------------------------
template <bool WB>
__global__ __launch_bounds__(256) void ln_add_kernel(
    float* __restrict__ io, const bf16* __restrict__ add,
    const float* __restrict__ w, const float* __restrict__ bias,
    bf16* __restrict__ bout)
{
    __shared__ float sbuf[4];
    const int row = blockIdx.x;
    const int tid = threadIdx.x;
    const size_t base = (size_t)row * O_;

    float x0 = io[base + tid] + (float)add[base + tid];
    float x1 = io[base + 256 + tid] + (float)add[base + 256 + tid];

    float s = x0 + x1;
#pragma unroll
    for (int off = 32; off >= 1; off >>= 1) s += __shfl_xor(s, off);
    if ((tid & 63) == 0) sbuf[tid >> 6] = s;
    __syncthreads();
    const float mean = (sbuf[0] + sbuf[1] + sbuf[2] + sbuf[3]) * (1.f / O_);
    __syncthreads();

    const float d0 = x0 - mean, d1 = x1 - mean;
    float ss = d0 * d0 + d1 * d1;
#pragma unroll
    for (int off = 32; off >= 1; off >>= 1) ss += __shfl_xor(ss, off);
    if ((tid & 63) == 0) sbuf[tid >> 6] = ss;
    __syncthreads();
    const float var = (sbuf[0] + sbuf[1] + sbuf[2] + sbuf[3]) * (1.f / O_);
    const float inv = rsqrtf(var + 1e-5f);

    const float y0 = d0 * inv * w[tid] + bias[tid];
    const float y1 = d1 * inv * w[tid + 256] + bias[tid + 256];
    io[base + tid] = y0;
    io[base + 256 + tid] = y1;
    if constexpr (WB) {
        bout[base + tid] = (bf16)y0;
        bout[base + 256 + tid] = (bf16)y1;
    }
}

// ---------------------------------------------------------------------------
extern "C" void kernel_launch(void* const* d_in, const int* in_sizes, int n_in,
                              void* d_out, int out_size, void* d_ws, size_t ws_size,
                              hipStream_t stream)
{
    const float* inputs = (const float*)d_in[0];
    const float* Wq = (const float*)d_in[1];
    const float* bq = (const float*)d_in[2];
    const float* Wk = (const float*)d_in[3];
    const float* bk = (const float*)d_in[4];
    const float* Wv = (const float*)d_in[5];
    const float* bv = (const float*)d_in[6];
    const float* Wr = (const float*)d_in[7];
    const float* br = (const float*)d_in[8];
    const float* Wo = (const float*)d_in[9];
    const float* bo = (const float*)d_in[10];
    const float* ln1w = (const float*)d_in[11];
    const float* ln1b = (const float*)d_in[12];
    const float* Wfc = (const float*)d_in[13];
    const float* bfc = (const float*)d_in[14];
    const float* ln2w = (const float*)d_in[15];
    const float* ln2b = (const float*)d_in[16];
    float* out = (float*)d_out;

    // Workspace layout (<= 118 MB; harness gives >= 128 MB):
    const size_t MB = 1024ull * 1024ull;
    char* ws = (char*)d_ws;
    bf16* qc   = (bf16*)(ws);                         // 32MB q -> attn out (in place)
    bf16* kb   = (bf16*)(ws + 32 * MB);               // 32MB k; after attn: res+fcb
    bf16* vt   = (bf16*)(ws + 64 * MB);               // 32MB v^T; after attn: xout
    bf16* resb = (bf16*)(ws + 32 * MB);               // 16MB residual (over kb)
    bf16* fcb  = (bf16*)(ws + 48 * MB);               // 16MB fc out (over kb)
    bf16* xout = (bf16*)(ws + 64 * MB);               // 16MB ln1 bf16 (over vt)
    bf16* xin  = (bf16*)(ws + 96 * MB);               // 16MB bf16 inputs
    bf16* wall = (bf16*)(ws + 112 * MB);              // 3MB  [3072][512] Wq|Wk|Wv
    bf16* wrt  = (bf16*)(ws + 115 * MB);              // 0.5MB [512][512]
    bf16* wot  = (bf16*)(ws + 115 * MB + 512 * 1024); // 1MB  [512][1024]
    bf16* wfct = (bf16*)(ws + 116 * MB + 512 * 1024); // 0.5MB [512][512]
    float* ball = (float*)(ws + 117 * MB);            // 12KB

    const dim3 blk(256);

    // prep
    conv_input_kernel<<<dim3(4096), blk, 0, stream>>>(inputs, xin);
    transpose_w_kernel<true ><<<dim3((NQ_ * D_) / 256), blk, 0, stream>>>(Wq, wall, D_, NQ_);
    transpose_w_kernel<true ><<<dim3((NQ_ * D_) / 256), blk, 0, stream>>>(Wk, wall + 1024 * 512, D_, NQ_);
    transpose_w_kernel<true ><<<dim3((NQ_ * D_) / 256), blk, 0, stream>>>(Wv, wall + 2048 * 512, D_, NQ_);
    transpose_w_kernel<false><<<dim3((D_ * O_) / 256), blk, 0, stream>>>(Wr, wrt, D_, O_);
    transpose_w_kernel<false><<<dim3((NQ_ * O_) / 256), blk, 0, stream>>>(Wo, wot, NQ_, O_);
    transpose_w_kernel<false><<<dim3((O_ * O_) / 256), blk, 0, stream>>>(Wfc, wfct, O_, O_);
    pack_bias_kernel<<<dim3(12), blk, 0, stream>>>(bq, bk, bv, ball);

    // fused QKV projection
    gemm_qkv_kernel<<<dim3(24, 128), blk, 0, stream>>>(xin, wall, ball, qc, kb, vt);
    // attention (in place over qc)
    mfma_attn_kernel<<<dim3(B_ * HN_ * 4), blk, 0, stream>>>(kb, vt, qc);
    // residual = inputs @ Wr + br (after attn so it can reuse kb space)
    gemm_std_kernel<0, false><<<dim3(4, 128), blk, 0, stream>>>(xin, wrt, br, resb, 512);
    // out = tanh(concat @ Wo + bo)
    gemm_std_kernel<2, true ><<<dim3(4, 128), blk, 0, stream>>>(qc, wot, bo, out, 1024);
    // out = LN1(out + res)  (+ bf16 copy for FC)
    ln_add_kernel<true ><<<dim3(M_), blk, 0, stream>>>(out, resb, ln1w, ln1b, xout);
    // fc = relu(out @ Wfc + bfc)
    gemm_std_kernel<1, false><<<dim3(4, 128), blk, 0, stream>>>(xout, wfct, bfc, fcb, 512);
    // out = LN2(fc + out)
    ln_add_kernel<false><<<dim3(M_), blk, 0, stream>>>(out, fcb, ln2w, ln2b, nullptr);
}

// Round 4
// 247.918 us; speedup vs baseline: 14.6317x; 1.3154x over previous
//
#include <hip/hip_runtime.h>
#include <hip/hip_bf16.h>

// Problem constants
#define B_  32
#define T_  512
#define D_  512
#define HD_ 64
#define HN_ 16
#define O_  512
#define M_  (B_ * T_)      // 16384 rows
#define NQ_ (HN_ * HD_)    // 1024 qkv cols

typedef __bf16 bf16;
typedef __attribute__((ext_vector_type(8))) __bf16 bf16x8;
typedef __attribute__((ext_vector_type(4))) __bf16 bf16x4;
typedef __attribute__((ext_vector_type(4))) float f32x4;

static __device__ __forceinline__ f32x4 mfma16(bf16x8 a, bf16x8 b, f32x4 c) {
    return __builtin_amdgcn_mfma_f32_16x16x32_bf16(a, b, c, 0, 0, 0);
}

// Direct global->LDS 16B copy.
static __device__ __forceinline__ void load_lds_16B(const bf16* g, bf16* l) {
    __builtin_amdgcn_global_load_lds(
        (const __attribute__((address_space(1))) unsigned int*)(unsigned long long)g,
        (__attribute__((address_space(3))) unsigned int*)(unsigned long long)l,
        16, 0, 0);
}

static __device__ __forceinline__ float fast_tanh(float x) {
    // 1 - 2/(e^{2x}+1); saturates correctly for |x| large. ~5 VALU ops.
    return 1.f - 2.f / (__expf(2.f * x) + 1.f);
}

// T1 chunked XCD swizzle: requires (gridDim.x*gridDim.y) % 8 == 0.
static __device__ __forceinline__ int2 swz_block() {
    const int nx = gridDim.x;
    const int nwg = nx * gridDim.y;
    int l = blockIdx.y * nx + blockIdx.x;        // dispatch-linear id
    l = (l & 7) * (nwg >> 3) + (l >> 3);         // XCD c owns a contiguous chunk
    return make_int2(l % nx, l / nx);
}

// ---------------------------------------------------------------------------
// Weight prep (LDS-tiled, coalesced both sides).
// ---------------------------------------------------------------------------
__global__ __launch_bounds__(256) void prep_headw_kernel(
    const float* __restrict__ Wq, const float* __restrict__ Wk,
    const float* __restrict__ Wv, bf16* __restrict__ wall)
{
    __shared__ bf16 tl[64][72];
    int id = blockIdx.x;                 // [src(3)][h(16)][kt(8)]
    const int kt = id & 7; id >>= 3;
    const int h = id & 15; id >>= 4;
    const float* src = (id == 0) ? Wq : (id == 1) ? Wk : Wv;
    bf16* dst = wall + (size_t)id * (1024 * 512);
    const int tid = threadIdx.x;
    const int k0 = kt * 64;
#pragma unroll
    for (int i = 0; i < 4; i++) {
        const int e = i * 256 + tid;
        const int kk = e >> 4, f4 = (e & 15) * 4;
        const f32x4 v = *(const f32x4*)(src + ((size_t)h * 512 + k0 + kk) * 64 + f4);
#pragma unroll
        for (int j = 0; j < 4; j++) tl[f4 + j][kk] = (bf16)v[j];
    }
    __syncthreads();
#pragma unroll
    for (int i = 0; i < 2; i++) {
        const int e = i * 256 + tid;
        const int f = e >> 3, kc = (e & 7) * 8;
        *(bf16x8*)(dst + ((size_t)h * 64 + f) * 512 + k0 + kc) = *(const bf16x8*)&tl[f][kc];
    }
}

__global__ __launch_bounds__(256) void prep_plain_kernel(
    const float* __restrict__ Wr, const float* __restrict__ Wo,
    const float* __restrict__ Wfc,
    bf16* __restrict__ wrt, bf16* __restrict__ wot, bf16* __restrict__ wfct)
{
    __shared__ bf16 tl[64][72];
    int id = blockIdx.x;                 // Wr:0..63  Wo:64..191  Wfc:192..255
    const float* src; bf16* dst; int K;
    if (id < 64)       { src = Wr;  dst = wrt;  K = 512;  }
    else if (id < 192) { src = Wo;  dst = wot;  K = 1024; id -= 64; }
    else               { src = Wfc; dst = wfct; K = 512;  id -= 192; }
    const int kt = id >> 3, nt = id & 7;  // N==512 -> 8 n-tiles
    const int k0 = kt * 64, n0 = nt * 64;
    const int tid = threadIdx.x;
#pragma unroll
    for (int i = 0; i < 4; i++) {
        const int e = i * 256 + tid;
        const int kk = e >> 4, n4 = (e & 15) * 4;
        const f32x4 v = *(const f32x4*)(src + (size_t)(k0 + kk) * 512 + n0 + n4);
#pragma unroll
        for (int j = 0; j < 4; j++) tl[n4 + j][kk] = (bf16)v[j];
    }
    __syncthreads();
#pragma unroll
    for (int i = 0; i < 2; i++) {
        const int e = i * 256 + tid;
        const int nn = e >> 3, kc = (e & 7) * 8;
        *(bf16x8*)(dst + (size_t)(n0 + nn) * K + k0 + kc) = *(const bf16x8*)&tl[nn][kc];
    }
}

__global__ __launch_bounds__(256) void conv_input_kernel(
    const float* __restrict__ in, bf16* __restrict__ out)
{
    const size_t i = ((size_t)blockIdx.x * 256 + threadIdx.x) * 8;
    f32x4 x0 = *(const f32x4*)(in + i);
    f32x4 x1 = *(const f32x4*)(in + i + 4);
    bf16x8 v;
    v[0] = (bf16)x0[0]; v[1] = (bf16)x0[1]; v[2] = (bf16)x0[2]; v[3] = (bf16)x0[3];
    v[4] = (bf16)x1[0]; v[5] = (bf16)x1[1]; v[6] = (bf16)x1[2]; v[7] = (bf16)x1[3];
    *(bf16x8*)(out + i) = v;
}

__global__ __launch_bounds__(256) void pack_bias_kernel(
    const float* __restrict__ bq, const float* __restrict__ bk,
    const float* __restrict__ bv, const float* __restrict__ br,
    float* __restrict__ ball)
{
    const int i = blockIdx.x * 256 + threadIdx.x;  // 0..3583
    float v = (i < 1024) ? bq[i]
            : (i < 2048) ? bk[i - 1024]
            : (i < 3072) ? bv[i - 2048] : br[i - 3072];
    ball[i] = v;
}

// ---------------------------------------------------------------------------
// GEMM mainloop, T3-minimum double-buffered pipeline (m248 recipe):
// issue STAGE(t+1) -> compute(t) -> vmcnt(0)+s_barrier (one barrier/K-step).
// 128x128 tile, BK=64, 4 waves (2x2), XOR-swizzled LDS (granule ^= row&7).
// ---------------------------------------------------------------------------
__device__ __forceinline__ void gemm_mainloop_db(
    const bf16* __restrict__ A, const bf16* __restrict__ Wt,
    const int K, const int m0, const int n0, const int tid,
    bf16 (*As)[128 * 64], bf16 (*Bs)[128 * 64], f32x4 (&acc)[4][4])
{
    const int lane = tid & 63;
    const int w = tid >> 6;
    const int wr = w >> 1, wc = w & 1;
    const int lr = lane & 15, lg = lane >> 4;
    const int nt = K >> 6;

    auto STAGE = [&](int buf, int k0) {
#pragma unroll
        for (int i = 0; i < 4; i++) {
            const int p = i * 256 + tid;
            const int row = p >> 3;
            const int g = (p & 7) ^ (row & 7);     // inverse-swizzled source granule
            load_lds_16B(A + (size_t)(m0 + row) * K + k0 + g * 8, As[buf] + p * 8);
            load_lds_16B(Wt + (size_t)(n0 + row) * K + k0 + g * 8, Bs[buf] + p * 8);
        }
    };

    STAGE(0, 0);
    asm volatile("s_waitcnt vmcnt(0)\n\ts_barrier" ::: "memory");

    for (int t = 0; t < nt; t++) {
        const int cur = t & 1;
        if (t + 1 < nt) STAGE(cur ^ 1, (t + 1) << 6);   // prefetch overlaps MFMA
#pragma unroll
        for (int kc = 0; kc < 2; kc++) {
            bf16x8 a[4], b[4];
#pragma unroll
            for (int mi = 0; mi < 4; mi++) {
                const int row = wr * 64 + mi * 16 + lr;
                a[mi] = *(const bf16x8*)&As[cur][row * 64 + ((((kc << 2) | lg) ^ (row & 7)) << 3)];
            }
#pragma unroll
            for (int nj = 0; nj < 4; nj++) {
                const int row = wc * 64 + nj * 16 + lr;
                b[nj] = *(const bf16x8*)&Bs[cur][row * 64 + ((((kc << 2) | lg) ^ (row & 7)) << 3)];
            }
#pragma unroll
            for (int mi = 0; mi < 4; mi++)
#pragma unroll
                for (int nj = 0; nj < 4; nj++)
                    acc[mi][nj] = mfma16(a[mi], b[nj], acc[mi][nj]);
        }
        asm volatile("s_waitcnt vmcnt(0)\n\ts_barrier" ::: "memory");
    }
}

// Fused QKV+R GEMM: N=3584 (q relu | k relu | v tanh transposed | r none). K=512.
__global__ __launch_bounds__(256) void gemm_qkvr_kernel(
    const bf16* __restrict__ A, const bf16* __restrict__ Wall,
    const float* __restrict__ ball,
    bf16* __restrict__ qc, bf16* __restrict__ kb, bf16* __restrict__ vt,
    bf16* __restrict__ resb)
{
    __shared__ bf16 As[2][128 * 64];
    __shared__ bf16 Bs[2][128 * 64];
    const int tid = threadIdx.x;
    const int2 bc = swz_block();
    const int m0 = bc.y * 128, n0 = bc.x * 128;
    f32x4 acc[4][4];
    const f32x4 zero4 = {0.f, 0.f, 0.f, 0.f};
#pragma unroll
    for (int i = 0; i < 4; i++)
#pragma unroll
        for (int j = 0; j < 4; j++) acc[i][j] = zero4;

    gemm_mainloop_db(A, Wall, 512, m0, n0, tid, As, Bs, acc);

    const int lane = tid & 63, w = tid >> 6;
    const int wr = w >> 1, wc = w & 1, lr = lane & 15, lg = lane >> 4;
    const int region = n0 >> 10;  // 0=q 1=k 2=v 3=r (128-tiles never straddle)
#pragma unroll
    for (int mi = 0; mi < 4; mi++) {
#pragma unroll
        for (int nj = 0; nj < 4; nj++) {
            const int n = n0 + wc * 64 + nj * 16 + lr;
            const float bn = ball[n];
            if (region == 2) {
                const int m = m0 + wr * 64 + mi * 16 + lg * 4;
                const int bb = m >> 9, t = m & 511;
                const int nn = n - 2048, hh = nn >> 6, f = nn & 63;
                bf16x4 st;
#pragma unroll
                for (int r = 0; r < 4; r++) st[r] = (bf16)fast_tanh(acc[mi][nj][r] + bn);
                *(bf16x4*)(vt + (((size_t)(bb * 16 + hh) * 64 + f) << 9) + t) = st;
            } else if (region == 3) {
                const int nn = n - 3072;
#pragma unroll
                for (int r = 0; r < 4; r++) {
                    const int m = m0 + wr * 64 + mi * 16 + lg * 4 + r;
                    resb[(size_t)m * 512 + nn] = (bf16)(acc[mi][nj][r] + bn);
                }
            } else {
                bf16* dst = region ? kb : qc;
                const int nn = n & 1023;
#pragma unroll
                for (int r = 0; r < 4; r++) {
                    const int m = m0 + wr * 64 + mi * 16 + lg * 4 + r;
                    dst[(size_t)m * 1024 + nn] = (bf16)fmaxf(acc[mi][nj][r] + bn, 0.f);
                }
            }
        }
    }
}

// Standard GEMM: N=512 pitch, bf16 out. ACT: 1 relu, 2 fast-tanh.
template <int ACT>
__global__ __launch_bounds__(256) void gemm_std_kernel(
    const bf16* __restrict__ A, const bf16* __restrict__ Wt,
    const float* __restrict__ bias, bf16* __restrict__ C, const int K)
{
    __shared__ bf16 As[2][128 * 64];
    __shared__ bf16 Bs[2][128 * 64];
    const int tid = threadIdx.x;
    const int2 bc = swz_block();
    const int m0 = bc.y * 128, n0 = bc.x * 128;
    f32x4 acc[4][4];
    const f32x4 zero4 = {0.f, 0.f, 0.f, 0.f};
#pragma unroll
    for (int i = 0; i < 4; i++)
#pragma unroll
        for (int j = 0; j < 4; j++) acc[i][j] = zero4;

    gemm_mainloop_db(A, Wt, K, m0, n0, tid, As, Bs, acc);

    const int lane = tid & 63, w = tid >> 6;
    const int wr = w >> 1, wc = w & 1, lr = lane & 15, lg = lane >> 4;
#pragma unroll
    for (int mi = 0; mi < 4; mi++) {
#pragma unroll
        for (int nj = 0; nj < 4; nj++) {
            const int n = n0 + wc * 64 + nj * 16 + lr;
            const float bn = bias[n];
#pragma unroll
            for (int r = 0; r < 4; r++) {
                const int m = m0 + wr * 64 + mi * 16 + lg * 4 + r;
                float v = acc[mi][nj][r] + bn;
                if constexpr (ACT == 1) v = fmaxf(v, 0.f);
                else if constexpr (ACT == 2) v = fast_tanh(v);
                C[(size_t)m * 512 + n] = (bf16)v;
            }
        }
    }
}

// ---------------------------------------------------------------------------
// MFMA flash attention, swapped-operand, T14 async-staged double-buffered K/V.
// Block = (b, h, 128 q rows); 4 waves x 32 q rows. S^T = mfma(K,Q) so each
// lane owns q = lane&15; softmax in-register. K rows stored under sigma() so
// S^T regs are already the PV B-frag layout. O^T = mfma(V^T, P^T).
// ---------------------------------------------------------------------------
static __device__ __forceinline__ int sigma_k(int t) {
    return (t & 32) | ((t & 4) << 2) | ((t & 24) >> 1) | (t & 3);
}

__global__ __launch_bounds__(256) void mfma_attn_kernel(
    const bf16* __restrict__ Kb, const bf16* __restrict__ Vt, bf16* __restrict__ QC)
{
    __shared__ bf16 Ks[2][64][72];
    __shared__ bf16 Vts[2][64][72];

    int l = blockIdx.x;
    l = (l & 7) * 256 + (l >> 3);      // XCD chunk swizzle: (b,h) stays on one XCD
    const int qb = l & 3;
    const int h = (l >> 2) & 15;
    const int b = l >> 6;
    const int tid = threadIdx.x;
    const int lane = tid & 63;
    const int w = tid >> 6;
    const int lr = lane & 15, lg = lane >> 4;

    const int qrow0 = qb * 128 + w * 32;
    const size_t qbase = ((size_t)b * T_ + qrow0) * NQ_ + h * 64;
    const int bh = b * HN_ + h;

    // Q fragments (B-frag: col q=lr, k=f) -- read before any QC write
    bf16x8 qf[2][2];
#pragma unroll
    for (int mi = 0; mi < 2; mi++)
#pragma unroll
        for (int kc = 0; kc < 2; kc++)
            qf[mi][kc] = *(const bf16x8*)(QC + qbase + (size_t)(mi * 16 + lr) * NQ_ + kc * 32 + lg * 8);

    const f32x4 zero4 = {0.f, 0.f, 0.f, 0.f};
    f32x4 o[2][4];
    float m_st[2] = {-1e30f, -1e30f}, l_st[2] = {0.f, 0.f};
#pragma unroll
    for (int mi = 0; mi < 2; mi++)
#pragma unroll
        for (int dj = 0; dj < 4; dj++) o[mi][dj] = zero4;

    const int nsb = 2 * qb + 2;

    bf16x8 kreg[2], vreg[2];
    auto LOADR = [&](int sb) {
#pragma unroll
        for (int i = 0; i < 2; i++) {
            const int ci = i * 256 + tid, row = ci >> 3, cc = ci & 7;
            kreg[i] = *(const bf16x8*)(Kb + ((size_t)b * T_ + sb * 64 + row) * NQ_ + h * 64 + cc * 8);
            vreg[i] = *(const bf16x8*)(Vt + ((size_t)bh * 64 + row) * T_ + sb * 64 + cc * 8);
        }
    };
    auto WRITE = [&](int buf) {
#pragma unroll
        for (int i = 0; i < 2; i++) {
            const int ci = i * 256 + tid, row = ci >> 3, cc = ci & 7;
            *(bf16x8*)&Ks[buf][sigma_k(row)][cc * 8] = kreg[i];
            *(bf16x8*)&Vts[buf][row][cc * 8] = vreg[i];
        }
    };

    LOADR(0); WRITE(0); __syncthreads();
    int cur = 0;

    for (int sb = 0; sb < nsb; sb++) {
        const bool pf = (sb + 1 < nsb);
        if (pf) LOADR(sb + 1);          // in flight during compute (T14)

        if (sb * 64 <= qrow0 + 31) {    // wave has unmasked work (wave-uniform)
            // S^T = K Q^T
            f32x4 sc[2][4];
#pragma unroll
            for (int mi = 0; mi < 2; mi++)
#pragma unroll
                for (int nj = 0; nj < 4; nj++) sc[mi][nj] = zero4;
#pragma unroll
            for (int kc = 0; kc < 2; kc++) {
                bf16x8 kf[4];
#pragma unroll
                for (int nj = 0; nj < 4; nj++)
                    kf[nj] = *(const bf16x8*)&Ks[cur][nj * 16 + lr][kc * 32 + lg * 8];
#pragma unroll
                for (int mi = 0; mi < 2; mi++)
#pragma unroll
                    for (int nj = 0; nj < 4; nj++)
                        sc[mi][nj] = mfma16(kf[nj], qf[mi][kc], sc[mi][nj]);
            }
            // scale + causal mask + in-register row max
            const bool needmask = (sb * 64 + 63 > qrow0);
            float tm[2];
#pragma unroll
            for (int mi = 0; mi < 2; mi++) {
                const int qg = qrow0 + mi * 16 + lr;
                float mx = -1e30f;
#pragma unroll
                for (int nj = 0; nj < 4; nj++) {
                    const int kvb = sb * 64 + ((nj >> 1) << 5) + ((nj & 1) << 2) + lg * 8;
#pragma unroll
                    for (int r = 0; r < 4; r++) {
                        float s = sc[mi][nj][r] * 0.125f;
                        if (needmask && (kvb + r > qg)) s = -1e30f;
                        sc[mi][nj][r] = s;
                        mx = fmaxf(mx, s);
                    }
                }
                mx = fmaxf(mx, __shfl_xor(mx, 16));
                mx = fmaxf(mx, __shfl_xor(mx, 32));
                tm[mi] = mx;
            }
            // defer-max (T13)
            const bool defer = (tm[0] <= m_st[0] + 8.f) && (tm[1] <= m_st[1] + 8.f);
            if (!__all(defer)) {
#pragma unroll
                for (int mi = 0; mi < 2; mi++) {
                    const float mn = fmaxf(m_st[mi], tm[mi]);
                    const float sf = __expf(m_st[mi] - mn);
                    m_st[mi] = mn;
                    l_st[mi] *= sf;
#pragma unroll
                    for (int dj = 0; dj < 4; dj++)
#pragma unroll
                        for (int r = 0; r < 4; r++) o[mi][dj][r] *= sf;
                }
            }
            // P = exp(S - m), row-sum, pack (already PV B-frag order)
            bf16x4 pk[2][4];
#pragma unroll
            for (int mi = 0; mi < 2; mi++) {
                float ts = 0.f;
#pragma unroll
                for (int nj = 0; nj < 4; nj++)
#pragma unroll
                    for (int r = 0; r < 4; r++) {
                        const float p = __expf(sc[mi][nj][r] - m_st[mi]);
                        ts += p;
                        pk[mi][nj][r] = (bf16)p;
                    }
                ts += __shfl_xor(ts, 16);
                ts += __shfl_xor(ts, 32);
                l_st[mi] += ts;
            }
            // O^T += V^T P^T
#pragma unroll
            for (int kc = 0; kc < 2; kc++) {
                bf16x8 vf[4], pf2[2];
#pragma unroll
                for (int mi = 0; mi < 2; mi++) {
                    bf16x8 t;
#pragma unroll
                    for (int r = 0; r < 4; r++) { t[r] = pk[mi][2 * kc][r]; t[r + 4] = pk[mi][2 * kc + 1][r]; }
                    pf2[mi] = t;
                }
#pragma unroll
                for (int dj = 0; dj < 4; dj++)
                    vf[dj] = *(const bf16x8*)&Vts[cur][dj * 16 + lr][kc * 32 + lg * 8];
#pragma unroll
                for (int mi = 0; mi < 2; mi++)
#pragma unroll
                    for (int dj = 0; dj < 4; dj++)
                        o[mi][dj] = mfma16(vf[dj], pf2[mi], o[mi][dj]);
            }
        }

        __syncthreads();                 // all done reading buf[cur^1]s last use
        if (pf) WRITE(cur ^ 1);          // land prefetched tile
        __syncthreads();                 // writes visible
        cur ^= 1;
    }

    // normalize + in-place store (O^T: lane owns q=lr col, d=lg*4+r rows)
#pragma unroll
    for (int mi = 0; mi < 2; mi++) {
        const float inv = 1.f / l_st[mi];
        const size_t rowoff = qbase + (size_t)(mi * 16 + lr) * NQ_;
#pragma unroll
        for (int dj = 0; dj < 4; dj++) {
            bf16x4 st;
#pragma unroll
            for (int r = 0; r < 4; r++) st[r] = (bf16)(o[mi][dj][r] * inv);
            *(bf16x4*)(QC + rowoff + dj * 16 + lg * 4) = st;
        }
    }
}

// ---------------------------------------------------------------------------
// LayerNorm, one 64-lane wave per 512-wide row, bf16x8 loads.
// out = LN(xa + xb) * w + b.  F32OUT: write f32 (final), else bf16.
// ---------------------------------------------------------------------------
template <bool F32OUT>
__global__ __launch_bounds__(256) void ln_kernel(
    const bf16* __restrict__ xa, const bf16* __restrict__ xb,
    const float* __restrict__ w, const float* __restrict__ bias,
    void* __restrict__ outv)
{
    const int row = blockIdx.x * 4 + (threadIdx.x >> 6);
    const int ln = threadIdx.x & 63;
    const size_t base = (size_t)row * 512 + ln * 8;
    const bf16x8 va = *(const bf16x8*)(xa + base);
    const bf16x8 vb = *(const bf16x8*)(xb + base);
    float x[8];
    float s = 0.f;
#pragma unroll
    for (int i = 0; i < 8; i++) { x[i] = (float)va[i] + (float)vb[i]; s += x[i]; }
#pragma unroll
    for (int off = 32; off >= 1; off >>= 1) s += __shfl_xor(s, off);
    const float mean = s * (1.f / 512.f);
    float ss = 0.f;
#pragma unroll
    for (int i = 0; i < 8; i++) { x[i] -= mean; ss += x[i] * x[i]; }
#pragma unroll
    for (int off = 32; off >= 1; off >>= 1) ss += __shfl_xor(ss, off);
    const float inv = rsqrtf(ss * (1.f / 512.f) + 1e-5f);
    const f32x4 w0 = *(const f32x4*)(w + ln * 8);
    const f32x4 w1 = *(const f32x4*)(w + ln * 8 + 4);
    const f32x4 b0 = *(const f32x4*)(bias + ln * 8);
    const f32x4 b1 = *(const f32x4*)(bias + ln * 8 + 4);
    if constexpr (F32OUT) {
        f32x4 y0, y1;
#pragma unroll
        for (int i = 0; i < 4; i++) {
            y0[i] = x[i] * inv * w0[i] + b0[i];
            y1[i] = x[4 + i] * inv * w1[i] + b1[i];
        }
        *(f32x4*)((float*)outv + base) = y0;
        *(f32x4*)((float*)outv + base + 4) = y1;
    } else {
        bf16x8 y;
#pragma unroll
        for (int i = 0; i < 4; i++) {
            y[i] = (bf16)(x[i] * inv * w0[i] + b0[i]);
            y[4 + i] = (bf16)(x[4 + i] * inv * w1[i] + b1[i]);
        }
        *(bf16x8*)((bf16*)outv + base) = y;
    }
}

// ---------------------------------------------------------------------------
extern "C" void kernel_launch(void* const* d_in, const int* in_sizes, int n_in,
                              void* d_out, int out_size, void* d_ws, size_t ws_size,
                              hipStream_t stream)
{
    const float* inputs = (const float*)d_in[0];
    const float* Wq = (const float*)d_in[1];
    const float* bq = (const float*)d_in[2];
    const float* Wk = (const float*)d_in[3];
    const float* bk = (const float*)d_in[4];
    const float* Wv = (const float*)d_in[5];
    const float* bv = (const float*)d_in[6];
    const float* Wr = (const float*)d_in[7];
    const float* br = (const float*)d_in[8];
    const float* Wo = (const float*)d_in[9];
    const float* bo = (const float*)d_in[10];
    const float* ln1w = (const float*)d_in[11];
    const float* ln1b = (const float*)d_in[12];
    const float* Wfc = (const float*)d_in[13];
    const float* bfc = (const float*)d_in[14];
    const float* ln2w = (const float*)d_in[15];
    const float* ln2b = (const float*)d_in[16];
    float* out = (float*)d_out;

    // Workspace layout (~117 MB):
    const size_t MB = 1024ull * 1024ull;
    char* ws = (char*)d_ws;
    bf16* qc   = (bf16*)(ws);               // 32MB [M][1024] q -> attn out (in place)
    bf16* kb   = (bf16*)(ws + 32 * MB);     // 32MB [M][1024] k; post-attn: att|ln1
    bf16* vt   = (bf16*)(ws + 64 * MB);     // 32MB v^T; post-attn: fcb
    bf16* xin  = (bf16*)(ws + 96 * MB);     // 16MB bf16 inputs
    bf16* wall = (bf16*)(ws + 112 * MB);    // 3.5MB [3584][512] Wq|Wk|Wv|Wr
    bf16* wot  = (bf16*)(ws + 112 * MB + 3670016);            // 1MB [512][1024]
    bf16* wfct = (bf16*)(ws + 112 * MB + 3670016 + 1048576);  // 0.5MB [512][512]
    float* ball = (float*)(ws + 112 * MB + 3670016 + 1048576 + 524288);  // 14KB
    bf16* wrt  = wall + (size_t)3072 * 512;
    // residual lives in d_out's spare bytes (bf16, 16MB of 32MB); consumed by
    // LN1 before LN2 overwrites d_out with the final f32 result.
    bf16* resb = (bf16*)d_out;
    bf16* att  = kb;                        // 16MB (kb dead after attention)
    bf16* ln1  = kb + (size_t)8 * MB;       // 16MB (second half of kb)
    bf16* fcb  = vt;                        // 16MB (vt dead after attention)

    const dim3 blk(256);

    // prep
    conv_input_kernel<<<dim3(4096), blk, 0, stream>>>(inputs, xin);
    prep_headw_kernel<<<dim3(384), blk, 0, stream>>>(Wq, Wk, Wv, wall);
    prep_plain_kernel<<<dim3(256), blk, 0, stream>>>(Wr, Wo, Wfc, wrt, wot, wfct);
    pack_bias_kernel<<<dim3(14), blk, 0, stream>>>(bq, bk, bv, br, ball);

    // fused QKV + residual projection (N=3584)
    gemm_qkvr_kernel<<<dim3(28, 128), blk, 0, stream>>>(xin, wall, ball, qc, kb, vt, resb);
    // attention (in place over qc)
    mfma_attn_kernel<<<dim3(B_ * HN_ * 4), blk, 0, stream>>>(kb, vt, qc);
    // att = tanh(concat @ Wo + bo)
    gemm_std_kernel<2><<<dim3(4, 128), blk, 0, stream>>>(qc, wot, bo, att, 1024);
    // ln1 = LN1(att + resb)
    ln_kernel<false><<<dim3(4096), blk, 0, stream>>>(att, resb, ln1w, ln1b, ln1);
    // fcb = relu(ln1 @ Wfc + bfc)
    gemm_std_kernel<1><<<dim3(4, 128), blk, 0, stream>>>(ln1, wfct, bfc, fcb, 512);
    // out = LN2(fcb + ln1)  (f32 final)
    ln_kernel<true ><<<dim3(4096), blk, 0, stream>>>(fcb, ln1, ln2w, ln2b, out);
}